// Round 5
// baseline (699.120 us; speedup 1.0000x reference)
//
#include <hip/hip_runtime.h>
#include <stdint.h>

// ---------- types ----------
typedef __attribute__((ext_vector_type(8))) short bf16x8;   // 8 bf16 in 4 VGPRs
typedef __attribute__((ext_vector_type(4))) float f32x4;

__device__ __forceinline__ float bf2f(short u){
  union { float f; uint32_t i; } v; v.i = ((uint32_t)(uint16_t)u) << 16; return v.f;
}
__device__ __forceinline__ short f2bf(float x){
  union { float f; uint32_t i; } v; v.f = x;
  uint32_t r = v.i + 0x7FFFu + ((v.i >> 16) & 1u);   // RNE
  return (short)(r >> 16);
}

// async global->LDS, 16B per lane; LDS dest = wave-uniform base + lane*16
__device__ __forceinline__ void gl_lds16(const short* g, short* l){
  __builtin_amdgcn_global_load_lds(
      (__attribute__((address_space(1))) void*)(short*)g,
      (__attribute__((address_space(3))) void*)l, 16, 0, 0);
}

// ---------- permutation tables (WIN=7, compile-time) ----------
__device__ const int d_DIAG[49] = {0,1,7,2,8,14,3,9,15,21,4,10,16,22,28,5,11,17,23,29,35,
  6,12,18,24,30,36,42,13,19,25,31,37,43,20,26,32,38,44,27,33,39,45,34,40,46,41,47,48};
__device__ const int d_ANTI[49] = {6,5,13,4,12,20,3,11,19,27,2,10,18,26,34,1,9,17,25,33,41,
  0,8,16,24,32,40,48,7,15,23,31,39,47,14,22,30,38,46,21,29,37,45,28,36,44,35,43,42};

__device__ __forceinline__ int perm_idx(int g, int l){
  if (g == 0) return l;
  if (g == 1) return (l % 7) * 7 + l / 7;  // V_IDX
  if (g == 2) return d_DIAG[l];
  return d_ANTI[l];
}

// ---------- prep: plain f32->bf16 converts (in_proj, post x4, x_proj_w, dt_proj_w) ----------
__global__ __launch_bounds__(256) void k_conv_all(
    const float* __restrict__ in_proj,
    const float* __restrict__ pw0, const float* __restrict__ pw1,
    const float* __restrict__ pw2, const float* __restrict__ pw3,
    const float* __restrict__ xpw, const float* __restrict__ dtw,
    short* __restrict__ inp_bf, short* __restrict__ postw_bf,
    short* __restrict__ xpw_bf, short* __restrict__ dtw_bf)
{
  int q = blockIdx.x*256 + threadIdx.x;   // quad index, total 332800
  const float* src; short* dst; int off;
  if (q < 65536){ src = in_proj; dst = inp_bf; off = q; }
  else if (q < 65536 + 262144){
    int r = q - 65536; int g = r >> 16; int loc = r & 65535;
    src = (g==0)?pw0:(g==1)?pw1:(g==2)?pw2:pw3;
    dst = postw_bf + g*262144; off = loc;
  }
  else if (q < 65536 + 262144 + 3072){ src = xpw; dst = xpw_bf; off = q - (65536+262144); }
  else { src = dtw; dst = dtw_bf; off = q - (65536+262144+3072); }
  float4 v = *(const float4*)(src + off*4);
  uint32_t p0 = (uint32_t)(uint16_t)f2bf(v.x) | ((uint32_t)(uint16_t)f2bf(v.y) << 16);
  uint32_t p1 = (uint32_t)(uint16_t)f2bf(v.z) | ((uint32_t)(uint16_t)f2bf(v.w) << 16);
  uint2 p; p.x = p0; p.y = p1;
  *(uint2*)(dst + off*4) = p;
}

// ---------- prep: LDS-tiled transpose+convert (pre_w x4 -> wpreT, out_proj -> woutT) ----------
__global__ __launch_bounds__(256) void k_transp(
    const float* __restrict__ pw0, const float* __restrict__ pw1,
    const float* __restrict__ pw2, const float* __restrict__ pw3,
    const float* __restrict__ outp,
    short* __restrict__ wpreT, short* __restrict__ woutT)
{
  __shared__ float tile[64][65];
  int which = blockIdx.y;
  const float* src = (which==0)?pw0:(which==1)?pw1:(which==2)?pw2:(which==3)?pw3:outp;
  short* dst = (which < 4) ? (wpreT + which*262144) : woutT;
  int bi = blockIdx.x >> 3, bj = blockIdx.x & 7;
  int r0 = bi*64, c0 = bj*64;
  int t = threadIdx.x;
  int row = t >> 2, cg = t & 3;
  const float4* s4 = (const float4*)(src + (r0+row)*512 + c0 + cg*16);
  #pragma unroll
  for (int i=0;i<4;i++){
    float4 v = s4[i];
    tile[row][cg*16 + i*4 + 0] = v.x;
    tile[row][cg*16 + i*4 + 1] = v.y;
    tile[row][cg*16 + i*4 + 2] = v.z;
    tile[row][cg*16 + i*4 + 3] = v.w;
  }
  __syncthreads();
  int oc = t >> 2;
  short tmp[16];
  #pragma unroll
  for (int i=0;i<16;i++) tmp[i] = f2bf(tile[cg*16 + i][oc]);
  short* dp = dst + (size_t)(c0+oc)*512 + r0 + cg*16;
  *(bf16x8*)(dp)     = *(bf16x8*)tmp;
  *(bf16x8*)(dp + 8) = *((bf16x8*)tmp + 1);
}

__global__ __launch_bounds__(256) void k_tok(const float* __restrict__ t, short* __restrict__ o){
  int i = (blockIdx.x*256 + threadIdx.x) * 4;
  float4 v = *(const float4*)(t + i);
  uint32_t p0 = (uint32_t)(uint16_t)f2bf(v.x) | ((uint32_t)(uint16_t)f2bf(v.y) << 16);
  uint32_t p1 = (uint32_t)(uint16_t)f2bf(v.z) | ((uint32_t)(uint16_t)f2bf(v.w) << 16);
  uint2 p; p.x = p0; p.y = p1;
  *(uint2*)(o + i) = p;
}

// ---------- prep: b_xz (blocks 0-7) + gains/biasc (block 8) ----------
__global__ __launch_bounds__(256) void k_bxz_gains(const float* __restrict__ in_proj,
    const float* __restrict__ b0, const float* __restrict__ b1,
    const float* __restrict__ b2, const float* __restrict__ b3,
    const float* __restrict__ gl,
    const float* __restrict__ pb0, const float* __restrict__ pb1,
    const float* __restrict__ pb2, const float* __restrict__ pb3,
    float* __restrict__ bxz, float* __restrict__ gains, float* __restrict__ biasc)
{
  if (blockIdx.x < 8){
    int idx = blockIdx.x*256 + threadIdx.x;   // 0..2047
    int g = idx >> 9, i = idx & 511;
    const float* bb = (g==0)?b0:(g==1)?b1:(g==2)?b2:b3;
    float s = 0.f;
    for (int t=0;t<512;t++) s += in_proj[i*512+t]*bb[t];
    bxz[idx] = s;
  } else {
    float m = fmaxf(fmaxf(gl[0], gl[1]), fmaxf(gl[2], gl[3]));
    float e0 = expf(gl[0]-m), e1 = expf(gl[1]-m), e2 = expf(gl[2]-m), e3 = expf(gl[3]-m);
    float s = e0+e1+e2+e3;
    float g0 = e0/s, g1 = e1/s, g2 = e2/s, g3 = e3/s;
    int t = threadIdx.x;
    if (t == 0){ gains[0]=g0; gains[1]=g1; gains[2]=g2; gains[3]=g3; }
    biasc[t]     = g0*pb0[t]     + g1*pb1[t]     + g2*pb2[t]     + g3*pb3[t];
    biasc[t+256] = g0*pb0[t+256] + g1*pb1[t+256] + g2*pb2[t+256] + g3*pb3[t+256];
  }
}

// ---------- register-GEMM core for the tiny weight-fuse GEMMs ----------
__device__ __forceinline__ void mfma_2x4_k(const short* a0, const short* a1,
    const short* b0, const short* b1, const short* b2, const short* b3,
    int K, f32x4 acc[2][4])
{
  for (int k0 = 0; k0 < K; k0 += 32){
    bf16x8 av0 = *(const bf16x8*)(a0 + k0);
    bf16x8 av1 = *(const bf16x8*)(a1 + k0);
    bf16x8 bv0 = *(const bf16x8*)(b0 + k0);
    bf16x8 bv1 = *(const bf16x8*)(b1 + k0);
    bf16x8 bv2 = *(const bf16x8*)(b2 + k0);
    bf16x8 bv3 = *(const bf16x8*)(b3 + k0);
    acc[0][0] = __builtin_amdgcn_mfma_f32_16x16x32_bf16(av0, bv0, acc[0][0],0,0,0);
    acc[0][1] = __builtin_amdgcn_mfma_f32_16x16x32_bf16(av0, bv1, acc[0][1],0,0,0);
    acc[0][2] = __builtin_amdgcn_mfma_f32_16x16x32_bf16(av0, bv2, acc[0][2],0,0,0);
    acc[0][3] = __builtin_amdgcn_mfma_f32_16x16x32_bf16(av0, bv3, acc[0][3],0,0,0);
    acc[1][0] = __builtin_amdgcn_mfma_f32_16x16x32_bf16(av1, bv0, acc[1][0],0,0,0);
    acc[1][1] = __builtin_amdgcn_mfma_f32_16x16x32_bf16(av1, bv1, acc[1][1],0,0,0);
    acc[1][2] = __builtin_amdgcn_mfma_f32_16x16x32_bf16(av1, bv2, acc[1][2],0,0,0);
    acc[1][3] = __builtin_amdgcn_mfma_f32_16x16x32_bf16(av1, bv3, acc[1][3],0,0,0);
  }
}

// ---------- merged weight-fuse: z<4 -> W_xz[g]; z>=4 -> Wog[g] ----------
__global__ __launch_bounds__(256) void k_wfuse(const short* __restrict__ inp_bf,
    const short* __restrict__ wpreT, const short* __restrict__ postw_bf,
    const short* __restrict__ woutT, const float* __restrict__ gains,
    short* __restrict__ wxz, short* __restrict__ wogc)
{
  int z = blockIdx.z; int g = z & 3, which = z >> 2;
  int bn = blockIdx.x * 64, bm = blockIdx.y * 128;
  int lane = threadIdx.x & 63, wave = threadIdx.x >> 6;
  int mr = lane & 15, qk = (lane >> 4) * 8, quad = lane >> 4;
  const short* Am = which ? (postw_bf + g*262144) : inp_bf;
  const short* Bm = which ? woutT : (wpreT + g*262144);
  const short* a0 = Am + (bm + wave*32 + mr)*512 + qk;
  const short* a1 = a0 + 16*512;
  const short* b0 = Bm + (bn +  0 + mr)*512 + qk;
  const short* b1 = Bm + (bn + 16 + mr)*512 + qk;
  const short* b2 = Bm + (bn + 32 + mr)*512 + qk;
  const short* b3 = Bm + (bn + 48 + mr)*512 + qk;
  f32x4 acc[2][4] = {};
  mfma_2x4_k(a0, a1, b0, b1, b2, b3, 512, acc);
  float gain = which ? gains[g] : 1.f;
  #pragma unroll
  for (int s=0;s<2;s++)
    #pragma unroll
    for (int t=0;t<4;t++)
      #pragma unroll
      for (int r=0;r<4;r++){
        int row = bm + wave*32 + s*16 + quad*4 + r;
        int col = bn + t*16 + mr;
        if (which) wogc[row*2048 + g*512 + col] = f2bf(gain * acc[s][t][r]);
        else       wxz[g*262144 + row*512 + col] = f2bf(acc[s][t][r]);
      }
}

// ---------- FUSED GEMM1+conv: batch-aligned 112-row tiles (2 batches, 98 real rows) ----------
// block: (bn: 128-ch tile, p: batch pair, g). GEMM (112x128, K=512) -> LDS -> conv3+SiLU -> ycat
__global__ __launch_bounds__(256) void k_gemm1c(const short* __restrict__ tok,
    const short* __restrict__ wxz, const float* __restrict__ bxz,
    const float* __restrict__ cxw, const float* __restrict__ cxb,
    const float* __restrict__ czw, const float* __restrict__ czb,
    short* __restrict__ ycat)
{
  // staging: As [4][112][8] (7168 B) + Bs [4][128][8] (8192 B); epilogue: xt [112][128] bf16 (28672 B)
  __shared__ __align__(16) char smem[28672];
  short* As = (short*)smem;
  short* Bs = (short*)(smem + 7168);
  short* xt = (short*)smem;

  int bn = blockIdx.x;          // 0..3
  int p  = blockIdx.y;          // 0..255
  int g  = blockIdx.z;          // 0..3
  int b0 = p*2;
  int tid = threadIdx.x, lane = tid & 63, w = tid >> 6;
  int mr = lane & 15, quad = lane >> 4;
  int wn = w*32;

  // staging setup: 15 chunks (A:0-6, B:7-14); wave w gets chunks w, w+4, w+8, w+12(<15)
  const short* gsrc[4]; short* ldst[4]; bool valid[4];
  #pragma unroll
  for (int i=0;i<4;i++){
    int c = w + i*4;
    valid[i] = (c < 15);
    if (c < 7){
      int f = c*64 + lane;
      int q = f / 112, row = f - q*112;
      int rrow = (row < 98) ? row : 0;
      int bl = (rrow >= 49) ? 1 : 0;
      int l = rrow - bl*49;
      int sl = perm_idx(g, l);
      gsrc[i] = tok + (size_t)((b0+bl)*49 + sl)*512 + q*8;
      ldst[i] = As + f*8;
    } else if (c < 15){
      int f = (c-7)*64 + lane;
      int q = f >> 7, row = f & 127;
      gsrc[i] = wxz + (size_t)g*262144 + (size_t)(bn*128 + row)*512 + q*8;
      ldst[i] = Bs + f*8;
    } else { gsrc[i] = tok; ldst[i] = As; }
  }

  f32x4 acc[7][2] = {};
  for (int ks = 0; ks < 16; ks++){
    #pragma unroll
    for (int i=0;i<4;i++){
      if (valid[i]) gl_lds16(gsrc[i], ldst[i]);
      gsrc[i] += 32;
    }
    __syncthreads();
    bf16x8 af[7], bfr[2];
    #pragma unroll
    for (int mt=0;mt<7;mt++) af[mt] = *(const bf16x8*)(As + (quad*112 + mt*16 + mr)*8);
    #pragma unroll
    for (int nt=0;nt<2;nt++) bfr[nt] = *(const bf16x8*)(Bs + (quad*128 + wn + nt*16 + mr)*8);
    #pragma unroll
    for (int mt=0;mt<7;mt++)
      #pragma unroll
      for (int nt=0;nt<2;nt++)
        acc[mt][nt] = __builtin_amdgcn_mfma_f32_16x16x32_bf16(af[mt], bfr[nt], acc[mt][nt],0,0,0);
    __syncthreads();
  }

  // epilogue 1: bias + bf16 round -> xt
  float biasv[2];
  #pragma unroll
  for (int nt=0;nt<2;nt++) biasv[nt] = bxz[g*512 + bn*128 + wn + nt*16 + mr];
  #pragma unroll
  for (int mt=0;mt<7;mt++)
    #pragma unroll
    for (int nt=0;nt<2;nt++)
      #pragma unroll
      for (int rr=0;rr<4;rr++){
        int row = mt*16 + quad*4 + rr;
        int col = wn + nt*16 + mr;
        xt[row*128 + col] = f2bf(acc[mt][nt][rr] + biasv[nt]);
      }
  __syncthreads();

  // epilogue 2: depthwise conv3 + SiLU -> ycat
  {
    int col = tid & 127, half = tid >> 7;
    int ch = bn*128 + col;
    bool isx = ch < 256;
    int cc = isx ? ch : ch - 256;
    const float* wsrc = isx ? cxw : czw;
    const float* bsrc = isx ? cxb : czb;
    float w0 = wsrc[cc*3], w1 = wsrc[cc*3+1], w2 = wsrc[cc*3+2], cb = bsrc[cc];
    #pragma unroll 7
    for (int i=0;i<49;i++){
      int row = 2*i + half;           // 0..97
      int bl = (row >= 49) ? 1 : 0;
      int l = row - bl*49;
      float v0 = bf2f(xt[row*128 + col]);
      float vm = (l > 0)  ? bf2f(xt[(row-1)*128 + col]) : 0.f;
      float vp = (l < 48) ? bf2f(xt[(row+1)*128 + col]) : 0.f;
      float x = w0*vm + w1*v0 + w2*vp + cb;
      ycat[(size_t)((b0+bl)*49 + l)*2048 + g*512 + ch] = f2bf(x / (1.f + __expf(-x)));
    }
  }
}

// ---------- k_xproj: x_proj GEMM + LN + dt GEMM + softplus ----------
__global__ __launch_bounds__(256) void k_xproj(const short* __restrict__ ycat,
    const short* __restrict__ xpw_bf, const float* __restrict__ lnw, const float* __restrict__ lnb,
    const short* __restrict__ dtw_bf, const float* __restrict__ dtb,
    short* __restrict__ dtln, float* __restrict__ bc)
{
  // LDS: xd f32 [128][52] = 26624 B ; xln_bf bf16 [128][40] = 10240 B
  __shared__ __align__(16) char smem[36864];
  float* xd = (float*)smem;
  short* xln = (short*)(smem + 26624);

  int bm = blockIdx.x * 128;
  int g = bm / 25088;                   // uniform per block (128 | 25088)
  int tid = threadIdx.x, lane = tid & 63, w = tid >> 6;
  int mr = lane & 15, quad = lane >> 4, qk = quad * 8;

  // ---- phase 1: x_dbl = u @ xpw^T  (tile 128x48, K=256) ----
  {
    const short* ap[2];
    #pragma unroll
    for (int s=0;s<2;s++)
      ap[s] = ycat + (size_t)(bm - g*25088 + w*32 + s*16 + mr)*2048 + g*512 + qk;
    f32x4 acc[2][3] = {};
    #pragma unroll
    for (int k0 = 0; k0 < 256; k0 += 32){
      bf16x8 av[2];
      #pragma unroll
      for (int s=0;s<2;s++) av[s] = *(const bf16x8*)(ap[s] + k0);
      #pragma unroll
      for (int t=0;t<3;t++){
        bf16x8 bv = *(const bf16x8*)(xpw_bf + (t*16 + mr)*256 + qk + k0);
        #pragma unroll
        for (int s=0;s<2;s++)
          acc[s][t] = __builtin_amdgcn_mfma_f32_16x16x32_bf16(av[s], bv, acc[s][t],0,0,0);
      }
    }
    #pragma unroll
    for (int s=0;s<2;s++)
      #pragma unroll
      for (int t=0;t<3;t++)
        #pragma unroll
        for (int r=0;r<4;r++)
          xd[(w*32 + s*16 + quad*4 + r)*52 + t*16 + mr] = acc[s][t][r];
  }
  __syncthreads();

  // ---- phase 2: LN per row (threads 0..127), dt-cols -> xln (bf16), B/C -> global ----
  if (tid < 128){
    f32x4* xr4 = (f32x4*)(xd + tid*52);
    f32x4 s = xr4[0];
    #pragma unroll
    for (int i=1;i<12;i++) s += xr4[i];
    float m = (s[0]+s[1]+s[2]+s[3]) * (1.f/48.f);
    f32x4 vs = {};
    #pragma unroll
    for (int i=0;i<12;i++){ f32x4 d = xr4[i] - m; vs += d*d; }
    float var = (vs[0]+vs[1]+vs[2]+vs[3]) * (1.f/48.f);
    float rstd = rsqrtf(var + 1e-5f);
    const f32x4* g4 = (const f32x4*)lnw;
    const f32x4* b4 = (const f32x4*)lnb;
    uint32_t* xlr = (uint32_t*)(xln + tid*40);
    #pragma unroll
    for (int i=0;i<8;i++){       // cols 0..31 -> xln bf16
      f32x4 v = (xr4[i] - m) * rstd * g4[i] + b4[i];
      xlr[2*i]   = (uint32_t)(uint16_t)f2bf(v[0]) | ((uint32_t)(uint16_t)f2bf(v[1]) << 16);
      xlr[2*i+1] = (uint32_t)(uint16_t)f2bf(v[2]) | ((uint32_t)(uint16_t)f2bf(v[3]) << 16);
    }
    f32x4* bco = (f32x4*)(bc + (size_t)(bm + tid)*16);
    #pragma unroll
    for (int i=8;i<12;i++)       // cols 32..47 -> bc f32
      bco[i-8] = (xr4[i] - m) * rstd * g4[i] + b4[i];
  }
  __syncthreads();

  // ---- phase 3: dt = xln[:,0:32] @ dtw^T (K=32, N=256) + bias + softplus -> dtln ----
  {
    bf16x8 a[2];
    #pragma unroll
    for (int s=0;s<2;s++)
      a[s] = *(const bf16x8*)(xln + (w*32 + s*16 + mr)*40 + qk);
    #pragma unroll 4
    for (int nt=0; nt<16; nt++){
      int col = nt*16 + mr;
      bf16x8 bv = *(const bf16x8*)(dtw_bf + col*32 + qk);
      float dtbv = dtb[col];
      #pragma unroll
      for (int s=0;s<2;s++){
        f32x4 acc = {};
        acc = __builtin_amdgcn_mfma_f32_16x16x32_bf16(a[s], bv, acc,0,0,0);
        #pragma unroll
        for (int r=0;r<4;r++){
          int grow = bm + w*32 + s*16 + quad*4 + r;
          float dtv = acc[r] + dtbv;
          float delta = (dtv > 20.f) ? dtv : log1pf(__expf(dtv));
          dtln[(size_t)grow*256 + col] = f2bf(delta);
        }
      }
    }
  }
}

// ---------- k_scan: selective scan, one block per gb, u->y in place ----------
__global__ __launch_bounds__(256) void k_scan(short* __restrict__ ycat,
    const short* __restrict__ dtln, const float* __restrict__ bc,
    const float* __restrict__ Alog, const float* __restrict__ Dp)
{
  __shared__ __align__(16) float bcs[784];   // [49][16]
  int gb = blockIdx.x; int g = gb >> 9, b = gb & 511;
  int d = threadIdx.x;
  if (d < 196) ((f32x4*)bcs)[d] = ((const f32x4*)(bc + (size_t)gb*784))[d];
  __syncthreads();

  float A[8], h[8];
  {
    f32x4 a0 = *(const f32x4*)(Alog + d*8);
    f32x4 a1 = *(const f32x4*)(Alog + d*8 + 4);
    #pragma unroll
    for (int n=0;n<4;n++){ A[n] = -__expf(a0[n]); A[n+4] = -__expf(a1[n]); h[n]=0.f; h[n+4]=0.f; }
  }
  float Dpar = Dp[d];

  const short* dptr = dtln + (size_t)gb*49*256 + d;
  short* uptr = ycat + (size_t)(b*49)*2048 + g*512 + d;

  float dn = bf2f(dptr[0]);
  float un = bf2f(uptr[0]);
  for (int l=0;l<49;l++){
    float delta = dn, u = un;
    if (l < 48){ dn = bf2f(dptr[(l+1)*256]); un = bf2f(uptr[(l+1)*2048]); }
    const f32x4* bcr = (const f32x4*)(bcs + l*16);
    f32x4 B0 = bcr[0], B1 = bcr[1], C0 = bcr[2], C1 = bcr[3];
    float du = delta * u;
    float y = 0.f;
    #pragma unroll
    for (int n=0;n<4;n++){
      h[n] = h[n]*__expf(delta*A[n]) + du*B0[n];
      y += h[n]*C0[n];
    }
    #pragma unroll
    for (int n=0;n<4;n++){
      h[n+4] = h[n+4]*__expf(delta*A[n+4]) + du*B1[n];
      y += h[n+4]*C1[n];
    }
    uptr[l*2048] = f2bf(y + Dpar*u);
  }
}

// ---------- final GEMM: 512-thread in-block split-K (two wave-groups of K=1024 each) ----------
// M=25088, N=512, K=2048; grid (4,196)
__global__ __launch_bounds__(512) void k_gemmF(const short* __restrict__ ycat,
    const short* __restrict__ wogc, const float* __restrict__ biasc,
    float* __restrict__ out)
{
  __shared__ __align__(16) char smem[32768];   // As[2][4096]s, Bs[2][4096]s; reduce: f32[8192]
  int bn = blockIdx.x * 128, bm = blockIdx.y * 128;
  int tid = threadIdx.x, lane = tid & 63, w = tid >> 6;
  int kg = w >> 2, ws = w & 3;
  short* As = (short*)smem + kg*4096;
  short* Bs = (short*)(smem + 16384) + kg*4096;
  float* red = (float*)smem;

  const short* aG[2]; const short* bG[2]; int ldsOff[2];
  #pragma unroll
  for (int i = 0; i < 2; i++){
    int c = ws*2 + i;
    int q = c >> 1, r = (c & 1)*64 + lane;
    aG[i] = ycat + (size_t)(bm + r)*2048 + kg*1024 + q*8;
    bG[i] = wogc + (size_t)(bn + r)*2048 + kg*1024 + q*8;
    ldsOff[i] = c*512;
  }

  int mr = lane & 15, quad = lane >> 4;
  int wm = (ws & 1)*64, wn = (ws >> 1)*64;
  f32x4 acc[4][4] = {};

  for (int ks = 0; ks < 32; ks++){
    #pragma unroll
    for (int i = 0; i < 2; i++){
      gl_lds16(aG[i], As + ldsOff[i]);
      gl_lds16(bG[i], Bs + ldsOff[i]);
      aG[i] += 32; bG[i] += 32;
    }
    __syncthreads();
    bf16x8 af[4], bfr[4];
    #pragma unroll
    for (int t = 0; t < 4; t++){
      af[t]  = *(const bf16x8*)(As + (quad*128 + wm + t*16 + mr)*8);
      bfr[t] = *(const bf16x8*)(Bs + (quad*128 + wn + t*16 + mr)*8);
    }
    #pragma unroll
    for (int mt = 0; mt < 4; mt++)
      #pragma unroll
      for (int nt = 0; nt < 4; nt++)
        acc[mt][nt] = __builtin_amdgcn_mfma_f32_16x16x32_bf16(af[mt], bfr[nt], acc[mt][nt],0,0,0);
    __syncthreads();
  }

  // cross-group reduce through LDS, 2 rounds of 64 rows; group0 writes out
  #pragma unroll
  for (int r = 0; r < 2; r++){
    if (kg == 1 && (ws & 1) == r){
      #pragma unroll
      for (int mt = 0; mt < 4; mt++)
        #pragma unroll
        for (int nt = 0; nt < 4; nt++)
          #pragma unroll
          for (int rr = 0; rr < 4; rr++)
            red[(mt*16 + quad*4 + rr)*128 + wn + nt*16 + mr] = acc[mt][nt][rr];
    }
    __syncthreads();
    if (kg == 0 && (ws & 1) == r){
      #pragma unroll
      for (int mt = 0; mt < 4; mt++)
        #pragma unroll
        for (int rr = 0; rr < 4; rr++){
          int lr = mt*16 + quad*4 + rr;
          int row = bm + r*64 + lr;
          float* orow = out + (size_t)row*512;
          #pragma unroll
          for (int nt = 0; nt < 4; nt++){
            int col = wn + nt*16 + mr;
            int colg = bn + col;
            orow[colg] = acc[mt][nt][rr] + red[lr*128 + col] + biasc[colg];
          }
        }
    }
    __syncthreads();
  }
}

// ---------- launch ----------
extern "C" void kernel_launch(void* const* d_in, const int* in_sizes, int n_in,
                              void* d_out, int out_size, void* d_ws, size_t ws_size,
                              hipStream_t stream)
{
  const float* tokens    = (const float*)d_in[0];
  const float* pre_w[4]  = {(const float*)d_in[1], (const float*)d_in[3], (const float*)d_in[5], (const float*)d_in[7]};
  const float* pre_b[4]  = {(const float*)d_in[2], (const float*)d_in[4], (const float*)d_in[6], (const float*)d_in[8]};
  const float* post_w[4] = {(const float*)d_in[9], (const float*)d_in[11], (const float*)d_in[13], (const float*)d_in[15]};
  const float* post_b[4] = {(const float*)d_in[10], (const float*)d_in[12], (const float*)d_in[14], (const float*)d_in[16]};
  const float* in_proj   = (const float*)d_in[17];
  const float* conv_x_w  = (const float*)d_in[18];
  const float* conv_x_b  = (const float*)d_in[19];
  const float* conv_z_w  = (const float*)d_in[20];
  const float* conv_z_b  = (const float*)d_in[21];
  const float* x_proj_w  = (const float*)d_in[22];
  const float* ln_w      = (const float*)d_in[23];
  const float* ln_b      = (const float*)d_in[24];
  const float* dt_proj_w = (const float*)d_in[25];
  const float* dt_proj_b = (const float*)d_in[26];
  const float* A_log     = (const float*)d_in[27];
  const float* D_param   = (const float*)d_in[28];
  const float* out_proj  = (const float*)d_in[29];
  const float* gate_log  = (const float*)d_in[30];

  char* ws = (char*)d_ws;
  size_t o = 0;
  short* tok_bf   = (short*)(ws + o); o += 25690112;   // 12845056 bf16
  short* wpreT    = (short*)(ws + o); o += 2097152;    // 4x 512x512 bf16 (transposed)
  short* inp_bf   = (short*)(ws + o); o += 524288;
  short* postw_bf = (short*)(ws + o); o += 2097152;
  short* woutT    = (short*)(ws + o); o += 524288;
  short* wogc     = (short*)(ws + o); o += 2097152;    // 512 x 2048 bf16
  short* wxz      = (short*)(ws + o); o += 2097152;    // 4x 512x512 bf16
  short* xpw_bf   = (short*)(ws + o); o += 24576;      // 48x256 bf16
  short* dtw_bf   = (short*)(ws + o); o += 16384;      // 256x32 bf16
  float* bxz      = (float*)(ws + o); o += 8192;
  float* gains    = (float*)(ws + o); o += 64;
  float* biasc    = (float*)(ws + o); o += 2048;
  short* dtln     = (short*)(ws + o); o += 51380224;   // 100352 x 256 bf16
  float* bc       = (float*)(ws + o); o += 6422528;    // 100352 x 16 f32
  short* ycat     = (short*)(ws + o); o += 102760448;  // 25088 x 2048 bf16

  k_conv_all<<<1300, 256, 0, stream>>>(in_proj,
      post_w[0], post_w[1], post_w[2], post_w[3],
      x_proj_w, dt_proj_w, inp_bf, postw_bf, xpw_bf, dtw_bf);
  k_transp<<<dim3(64,5), 256, 0, stream>>>(pre_w[0], pre_w[1], pre_w[2], pre_w[3],
      out_proj, wpreT, woutT);
  k_tok<<<12544, 256, 0, stream>>>(tokens, tok_bf);
  k_bxz_gains<<<9, 256, 0, stream>>>(in_proj, pre_b[0], pre_b[1], pre_b[2], pre_b[3],
      gate_log, post_b[0], post_b[1], post_b[2], post_b[3], bxz, gains, biasc);
  k_wfuse<<<dim3(8,4,8), 256, 0, stream>>>(inp_bf, wpreT, postw_bf, woutT, gains, wxz, wogc);
  k_gemm1c<<<dim3(4,256,4), 256, 0, stream>>>(tok_bf, wxz, bxz,
      conv_x_w, conv_x_b, conv_z_w, conv_z_b, ycat);
  k_xproj<<<784, 256, 0, stream>>>(ycat, xpw_bf, ln_w, ln_b, dtw_bf, dt_proj_b, dtln, bc);
  k_scan<<<2048, 256, 0, stream>>>(ycat, dtln, bc, A_log, D_param);
  k_gemmF<<<dim3(4,196), 512, 0, stream>>>(ycat, wogc, biasc, (float*)d_out);
}